// Round 2
// baseline (283.559 us; speedup 1.0000x reference)
//
#include <hip/hip_runtime.h>

// Magnus2: x_{n+1} = E_n x_n with a shared 2x2 E_n across the batch.
// (1) build E_n in parallel, (2) prefix-product scan of 2x2 matrices
// (single block, Hillis-Steele over 1024 chunk-products),
// (3) out[n] = P_n @ x0, store-bound f32 write (256 MB).

struct M2 { float a, b, c, d; };

__device__ __forceinline__ M2 mmul(const M2& X, const M2& Y) {
    // X * Y (X applied after Y)
    M2 r;
    r.a = X.a * Y.a + X.b * Y.c;
    r.b = X.a * Y.b + X.b * Y.d;
    r.c = X.c * Y.a + X.d * Y.c;
    r.d = X.c * Y.b + X.d * Y.d;
    return r;
}

// ---------------- Kernel 0: build E_n (n in [0, T-1)) ----------------
__global__ void e_kernel(const float* __restrict__ t,
                         const float* __restrict__ p_w2,
                         const float* __restrict__ p_g0,
                         const float* __restrict__ p_ga,
                         const float* __restrict__ p_wd,
                         const int* __restrict__ p_uc,
                         float4* __restrict__ E, int T) {
    int n = blockIdx.x * blockDim.x + threadIdx.x;
    if (n >= T - 1) return;
    float w2 = *p_w2, g0 = *p_g0, ga = *p_ga, wd = *p_wd;
    int uc = *p_uc;

    float t0 = t[n], t1 = t[n + 1];
    float dt = t1 - t0;
    float tm = t0 + dt * 0.5f;

    float gam0 = g0 * (1.0f + ga * sinf(wd * t0));
    float gamm = g0 * (1.0f + ga * sinf(wd * tm));
    float gam1 = g0 * (1.0f + ga * sinf(wd * t1));

    // Omega = A_mid*dt (+ dt^2/12 * [A0,A1]);  [A0,A1] = [[0, d],[w2*d, 0]], d = g0-g1
    float Oa = 0.0f;
    float Ob = dt;
    float Oc = -w2 * dt;
    float Od = -gamm * dt;
    if (uc) {
        float k = dt * dt * (1.0f / 12.0f);
        float del = gam0 - gam1;
        Ob += k * del;
        Oc += k * (w2 * del);
    }

    // expm of 2x2
    float m   = 0.5f * (Oa + Od);
    float det = Oa * Od - Ob * Oc;
    float delta = m * m - det;
    float s = sqrtf(fabsf(delta));
    bool pos = delta >= 0.0f;
    bool small_ = s < 1e-6f;
    float s_safe = small_ ? 1.0f : s;
    float cosl = pos ? coshf(s) : cosf(s);
    float sn   = pos ? sinhf(s_safe) : sinf(s_safe);
    float sinch = small_ ? 1.0f : sn / s_safe;
    float em = expf(m);

    float4 Ev;
    Ev.x = em * (cosl + sinch * (Oa - m));
    Ev.y = em * (sinch * Ob);
    Ev.z = em * (sinch * Oc);
    Ev.w = em * (cosl + sinch * (Od - m));
    E[n] = Ev;
}

// ---------------- Kernel 1: prefix product scan (single block) ----------------
// P[0] = I; P[n] = E_{n-1} ... E_0 for n in [1, T-1]. Requires T <= 8192.
__global__ __launch_bounds__(1024) void scan_kernel(const float4* __restrict__ E,
                                                    float4* __restrict__ P, int T) {
    __shared__ float4 lds[1024];
    const int j = threadIdx.x;
    const int base = j * 8;

    // local inclusive chain over 8 consecutive matrices (identity-padded)
    M2 S[8];
    #pragma unroll
    for (int mi = 0; mi < 8; ++mi) {
        int k = base + mi;
        M2 Mk;
        if (k < T - 1) {
            float4 e = E[k];
            Mk.a = e.x; Mk.b = e.y; Mk.c = e.z; Mk.d = e.w;
        } else {
            Mk.a = 1.0f; Mk.b = 0.0f; Mk.c = 0.0f; Mk.d = 1.0f;
        }
        S[mi] = (mi == 0) ? Mk : mmul(Mk, S[mi - 1]);
    }

    // block-wide inclusive scan of chunk products (newer-on-left combine)
    M2 acc = S[7];
    lds[j] = make_float4(acc.a, acc.b, acc.c, acc.d);
    for (int d = 1; d < 1024; d <<= 1) {
        __syncthreads();
        M2 prev;
        bool act = (j >= d);
        if (act) {
            float4 p = lds[j - d];
            prev.a = p.x; prev.b = p.y; prev.c = p.z; prev.d = p.w;
        }
        __syncthreads();
        if (act) {
            acc = mmul(acc, prev);
            lds[j] = make_float4(acc.a, acc.b, acc.c, acc.d);
        }
    }
    __syncthreads();

    // exclusive offset for this chunk
    M2 Bm;
    if (j == 0) { Bm.a = 1.0f; Bm.b = 0.0f; Bm.c = 0.0f; Bm.d = 1.0f; }
    else {
        float4 p = lds[j - 1];
        Bm.a = p.x; Bm.b = p.y; Bm.c = p.z; Bm.d = p.w;
    }

    if (j == 0) P[0] = make_float4(1.0f, 0.0f, 0.0f, 1.0f);
    #pragma unroll
    for (int mi = 0; mi < 8; ++mi) {
        int g = base + mi + 1;      // P index this slot produces
        if (g < T) {
            M2 r = mmul(S[mi], Bm);
            P[g] = make_float4(r.a, r.b, r.c, r.d);
        }
    }
}

// ---------------- Kernel 2: out[n] = P_n @ x0, f32 store ----------------
__global__ __launch_bounds__(256) void out_kernel(const float4* __restrict__ P,
                                                  const float* __restrict__ x0,
                                                  float* __restrict__ out, int B) {
    const int n = blockIdx.x;
    const float4 p = P[n];
    const float4* xr0 = (const float4*)x0;          // row 0 of x0
    const float4* xr1 = xr0 + (B >> 2);             // row 1 of x0
    float4* o = (float4*)(out + (size_t)n * (size_t)(2 * B));
    const int q = B >> 2;                            // float4 groups per row

    for (int g = threadIdx.x; g < q; g += blockDim.x) {
        float4 u = xr0[g];
        float4 v = xr1[g];
        float4 r0, r1;
        r0.x = p.x * u.x + p.y * v.x;
        r0.y = p.x * u.y + p.y * v.y;
        r0.z = p.x * u.z + p.y * v.z;
        r0.w = p.x * u.w + p.y * v.w;
        r1.x = p.z * u.x + p.w * v.x;
        r1.y = p.z * u.y + p.w * v.y;
        r1.z = p.z * u.z + p.w * v.z;
        r1.w = p.z * u.w + p.w * v.w;
        o[g]     = r0;
        o[q + g] = r1;
    }
}

extern "C" void kernel_launch(void* const* d_in, const int* in_sizes, int n_in,
                              void* d_out, int out_size, void* d_ws, size_t ws_size,
                              hipStream_t stream) {
    const float* t   = (const float*)d_in[0];
    const float* x0  = (const float*)d_in[1];
    const float* w2  = (const float*)d_in[2];
    const float* g0  = (const float*)d_in[3];
    const float* ga  = (const float*)d_in[4];
    const float* wd  = (const float*)d_in[5];
    const int*   uc  = (const int*)d_in[6];

    const int T = in_sizes[0];          // 8192
    const int B = in_sizes[1] / 2;      // 4096

    float4* E = (float4*)d_ws;          // T float4
    float4* P = E + T;                  // T float4

    float* out = (float*)d_out;

    int nE = T - 1;
    e_kernel<<<(nE + 255) / 256, 256, 0, stream>>>(t, w2, g0, ga, wd, uc, E, T);
    scan_kernel<<<1, 1024, 0, stream>>>(E, P, T);
    out_kernel<<<T, 256, 0, stream>>>(P, x0, out, B);
}